// Round 1
// baseline (251.340 us; speedup 1.0000x reference)
//
#include <hip/hip_runtime.h>

#define NNODES 100000
#define NEDGES 1600000
#define FD 128

constexpr int BM = 32;  // rows of X per block in the GEMM

// ---------------------------------------------------------------------------
// Kernel 1: support = X @ W   (fp32, LDS-tiled, 4 rows x 4 cols per thread)
// ---------------------------------------------------------------------------
__global__ __launch_bounds__(256) void gemm_xw(const float* __restrict__ X,
                                               const float* __restrict__ W,
                                               float* __restrict__ S) {
    __shared__ float Ws[FD][FD];   // 64 KB: W[k][c]
    __shared__ float Xs[BM][FD];   // 16 KB: X rows

    const int tid = threadIdx.x;
    const int row0 = blockIdx.x * BM;

    // Stage W (coalesced float4): 16384 floats / (256 thr * 4) = 16 iters
    for (int i = tid * 4; i < FD * FD; i += 256 * 4)
        *(float4*)&Ws[i >> 7][i & 127] = *(const float4*)&W[i];
    // Stage X tile (coalesced float4): 4096 floats -> 4 iters
    for (int i = tid * 4; i < BM * FD; i += 256 * 4)
        *(float4*)&Xs[i >> 7][i & 127] = *(const float4*)&X[row0 * FD + i];
    __syncthreads();

    const int cq = (tid & 31) * 4;   // column base (0..124, step 4)
    const int rg = (tid >> 5) * 4;   // row base within tile (0..28, step 4)

    float4 acc[4];
    acc[0] = make_float4(0.f, 0.f, 0.f, 0.f);
    acc[1] = acc[0]; acc[2] = acc[0]; acc[3] = acc[0];

    #pragma unroll 8
    for (int kk = 0; kk < FD; kk += 4) {
        const float4 w0 = *(const float4*)&Ws[kk + 0][cq];
        const float4 w1 = *(const float4*)&Ws[kk + 1][cq];
        const float4 w2 = *(const float4*)&Ws[kk + 2][cq];
        const float4 w3 = *(const float4*)&Ws[kk + 3][cq];
        #pragma unroll
        for (int j = 0; j < 4; ++j) {
            const float4 x = *(const float4*)&Xs[rg + j][kk];
            acc[j].x = fmaf(x.x, w0.x, acc[j].x);
            acc[j].x = fmaf(x.y, w1.x, acc[j].x);
            acc[j].x = fmaf(x.z, w2.x, acc[j].x);
            acc[j].x = fmaf(x.w, w3.x, acc[j].x);
            acc[j].y = fmaf(x.x, w0.y, acc[j].y);
            acc[j].y = fmaf(x.y, w1.y, acc[j].y);
            acc[j].y = fmaf(x.z, w2.y, acc[j].y);
            acc[j].y = fmaf(x.w, w3.y, acc[j].y);
            acc[j].z = fmaf(x.x, w0.z, acc[j].z);
            acc[j].z = fmaf(x.y, w1.z, acc[j].z);
            acc[j].z = fmaf(x.z, w2.z, acc[j].z);
            acc[j].z = fmaf(x.w, w3.z, acc[j].z);
            acc[j].w = fmaf(x.x, w0.w, acc[j].w);
            acc[j].w = fmaf(x.y, w1.w, acc[j].w);
            acc[j].w = fmaf(x.z, w2.w, acc[j].w);
            acc[j].w = fmaf(x.w, w3.w, acc[j].w);
        }
    }

    #pragma unroll
    for (int j = 0; j < 4; ++j)
        *(float4*)&S[(row0 + rg + j) * FD + cq] = acc[j];
}

// ---------------------------------------------------------------------------
// Kernel 2: out[n][f] = bias[f]   (so SpMM can accumulate on top)
// ---------------------------------------------------------------------------
__global__ __launch_bounds__(256) void init_out(float* __restrict__ out,
                                                const float* __restrict__ bias) {
    const int i = (blockIdx.x * 256 + threadIdx.x) * 4;  // 12.8M elems, exact grid
    const float4 b = *(const float4*)&bias[i & 127];
    *(float4*)&out[i] = b;
}

// ---------------------------------------------------------------------------
// Kernel 3: out[row] += val * S[col]  over sorted-by-row COO edges.
// One wave per 196-edge chunk; lane owns features [2*lane, 2*lane+1].
// Register accumulate while row unchanged; atomicAdd flush on row change
// (handles chunk-boundary segments shared between waves).
// ---------------------------------------------------------------------------
__global__ __launch_bounds__(256) void spmm_coo(const int* __restrict__ rows,
                                                const int* __restrict__ cols,
                                                const float* __restrict__ vals,
                                                const float* __restrict__ S,
                                                float* __restrict__ out) {
    const int wave = (blockIdx.x * 256 + threadIdx.x) >> 6;
    const int lane = threadIdx.x & 63;
    const int EPW = 196;                       // 8192 waves * 196 >= 1.6M
    const int e0 = wave * EPW;
    if (e0 >= NEDGES) return;
    const int e1 = min(e0 + EPW, NEDGES);
    const int fb = lane * 2;

    float ax = 0.f, ay = 0.f;
    int cur = rows[e0];

    for (int b = e0; b < e1; b += 64) {
        const int n = min(64, e1 - b);
        int r = 0, c = 0;
        float v = 0.f;
        if (lane < n) {
            r = rows[b + lane];
            c = cols[b + lane];
            v = vals[b + lane];
        }
        for (int j = 0; j < n; ++j) {
            const int rj = __shfl(r, j);
            const int cj = __shfl(c, j);
            const float vj = __shfl(v, j);
            if (rj != cur) {                    // wave-uniform branch
                atomicAdd(&out[cur * FD + fb], ax);
                atomicAdd(&out[cur * FD + fb + 1], ay);
                ax = 0.f; ay = 0.f;
                cur = rj;
            }
            const float2 s = *(const float2*)&S[cj * FD + fb];
            ax = fmaf(vj, s.x, ax);
            ay = fmaf(vj, s.y, ay);
        }
    }
    atomicAdd(&out[cur * FD + fb], ax);
    atomicAdd(&out[cur * FD + fb + 1], ay);
}

// ---------------------------------------------------------------------------
extern "C" void kernel_launch(void* const* d_in, const int* in_sizes, int n_in,
                              void* d_out, int out_size, void* d_ws, size_t ws_size,
                              hipStream_t stream) {
    const float* X    = (const float*)d_in[0];
    const int*   erow = (const int*)d_in[1];
    const int*   ecol = (const int*)d_in[2];
    const float* eval_= (const float*)d_in[3];
    const float* W    = (const float*)d_in[4];
    const float* bias = (const float*)d_in[5];
    float* out = (float*)d_out;
    float* S   = (float*)d_ws;   // 100000*128*4 = 51.2 MB scratch

    gemm_xw<<<NNODES / BM, 256, 0, stream>>>(X, W, S);              // 3125 blocks
    init_out<<<NNODES * FD / 4 / 256, 256, 0, stream>>>(out, bias); // 12500 blocks
    spmm_coo<<<2048, 256, 0, stream>>>(erow, ecol, eval_, S, out);  // 8192 waves
}

// Round 2
// 133.158 us; speedup vs baseline: 1.8875x; 1.8875x over previous
//
#include <hip/hip_runtime.h>

typedef unsigned int uint;
typedef unsigned short ushort;

#define NNODES 100000
#define NEDGES 1600000
#define FD 128
#define BM 64
#define BK 32

// round-to-nearest-even f32 -> bf16
__device__ __forceinline__ ushort f2bf(float f) {
    uint u = __float_as_uint(f);
    u += 0x7fffu + ((u >> 16) & 1u);
    return (ushort)(u >> 16);
}

// ---------------------------------------------------------------------------
// Kernel 1: S = X @ W, fp32 compute, bf16 store.
// 64x128 output tile / block, K tiled by 32. X staged TRANSPOSED in LDS so
// the compute loop is pure ds_read_b128 broadcasts (conflict-free).
// LDS = 32*68*4 + 32*128*4 = 25.2 KB -> ~5 blocks/CU.
// ---------------------------------------------------------------------------
__global__ __launch_bounds__(256) void gemm_xw_bf16(const float* __restrict__ X,
                                                    const float* __restrict__ W,
                                                    ushort* __restrict__ S) {
    __shared__ float XsT[BK][BM + 4];   // stride 68: keeps float4 16B-aligned
    __shared__ float Ws[BK][FD];

    const int tid = threadIdx.x;
    const int row0 = blockIdx.x * BM;
    const int rg = (tid >> 5) * 8;      // 8 rows per thread
    const int cq = (tid & 31) * 4;      // 4 cols per thread

    float4 acc[8];
    #pragma unroll
    for (int j = 0; j < 8; ++j) acc[j] = make_float4(0.f, 0.f, 0.f, 0.f);

    for (int k0 = 0; k0 < FD; k0 += BK) {
        // stage X tile 64x32 -> transposed LDS
        #pragma unroll
        for (int it = 0; it < 2; ++it) {
            const int flat = (tid + it * 256) * 4;
            const int r = flat >> 5, k = flat & 31;
            const int grow = min(row0 + r, NNODES - 1);   // tail clamp
            const float4 g = *(const float4*)&X[grow * FD + k0 + k];
            XsT[k + 0][r] = g.x;
            XsT[k + 1][r] = g.y;
            XsT[k + 2][r] = g.z;
            XsT[k + 3][r] = g.w;
        }
        // stage W tile 32x128 (row-major copy)
        #pragma unroll
        for (int it = 0; it < 4; ++it) {
            const int flat = (tid + it * 256) * 4;
            const int k = flat >> 7, c = flat & 127;
            *(float4*)&Ws[k][c] = *(const float4*)&W[(k0 + k) * FD + c];
        }
        __syncthreads();

        #pragma unroll 8
        for (int kk = 0; kk < BK; ++kk) {
            const float4 xa = *(const float4*)&XsT[kk][rg];
            const float4 xb = *(const float4*)&XsT[kk][rg + 4];
            const float4 w  = *(const float4*)&Ws[kk][cq];
#define FMA4(A, s) A.x = fmaf(s, w.x, A.x); A.y = fmaf(s, w.y, A.y); \
                   A.z = fmaf(s, w.z, A.z); A.w = fmaf(s, w.w, A.w);
            FMA4(acc[0], xa.x) FMA4(acc[1], xa.y)
            FMA4(acc[2], xa.z) FMA4(acc[3], xa.w)
            FMA4(acc[4], xb.x) FMA4(acc[5], xb.y)
            FMA4(acc[6], xb.z) FMA4(acc[7], xb.w)
#undef FMA4
        }
        __syncthreads();
    }

    // store bf16 (S is padded to 100032 rows; garbage tail rows never read)
    #pragma unroll
    for (int j = 0; j < 8; ++j) {
        ushort4 o;
        o.x = f2bf(acc[j].x); o.y = f2bf(acc[j].y);
        o.z = f2bf(acc[j].z); o.w = f2bf(acc[j].w);
        *(ushort4*)&S[(row0 + rg + j) * FD + cq] = o;
    }
}

// ---------------------------------------------------------------------------
// Kernel 2: row_ptr[r] = lower_bound(edge_row, r)  (edge_row is sorted)
// ---------------------------------------------------------------------------
__global__ __launch_bounds__(256) void build_rowptr(const int* __restrict__ rows,
                                                    int* __restrict__ ptr) {
    const int r = blockIdx.x * 256 + threadIdx.x;
    if (r > NNODES) return;
    int lo = 0, hi = NEDGES;
    while (lo < hi) {
        const int mid = (lo + hi) >> 1;
        const bool lt = rows[mid] < r;
        lo = lt ? mid + 1 : lo;
        hi = lt ? hi : mid;
    }
    ptr[r] = lo;
}

// ---------------------------------------------------------------------------
// Kernel 3: one wave per output row. Branchless gather loop: edge meta read
// wave-uniform (broadcast), S row gathered as bf16x2/lane, fp32 accumulate,
// direct store of acc + bias. No atomics, no shfl chains.
// ---------------------------------------------------------------------------
__global__ __launch_bounds__(256) void spmm_csr(const int* __restrict__ ptr,
                                                const int* __restrict__ cols,
                                                const float* __restrict__ vals,
                                                const ushort* __restrict__ S,
                                                const float* __restrict__ bias,
                                                float* __restrict__ out) {
    const int row = (blockIdx.x * 256 + threadIdx.x) >> 6;
    if (row >= NNODES) return;
    const int lane = threadIdx.x & 63;
    const int f = lane * 2;

    const int e0 = ptr[row];
    const int e1 = ptr[row + 1];

    float ax = 0.f, ay = 0.f;
    #pragma unroll 4
    for (int e = e0; e < e1; ++e) {
        const int c = cols[e];           // wave-uniform -> broadcast
        const float v = vals[e];
        const uint s2 = *(const uint*)&S[c * FD + f];
        ax = fmaf(v, __uint_as_float(s2 << 16), ax);
        ay = fmaf(v, __uint_as_float(s2 & 0xffff0000u), ay);
    }

    float2 o;
    o.x = ax + bias[f];
    o.y = ay + bias[f + 1];
    *(float2*)&out[row * FD + f] = o;
}

// ---------------------------------------------------------------------------
extern "C" void kernel_launch(void* const* d_in, const int* in_sizes, int n_in,
                              void* d_out, int out_size, void* d_ws, size_t ws_size,
                              hipStream_t stream) {
    const float* X    = (const float*)d_in[0];
    const int*   erow = (const int*)d_in[1];
    const int*   ecol = (const int*)d_in[2];
    const float* eval_= (const float*)d_in[3];
    const float* W    = (const float*)d_in[4];
    const float* bias = (const float*)d_in[5];
    float* out = (float*)d_out;

    ushort* S  = (ushort*)d_ws;                              // 100032*128*2 = 25.6 MB
    int* rptr  = (int*)((char*)d_ws + 26 * 1024 * 1024);     // 100001 ints

    gemm_xw_bf16<<<(NNODES + BM - 1) / BM, 256, 0, stream>>>(X, W, S);     // 1563 blocks
    build_rowptr<<<(NNODES + 256) / 256, 256, 0, stream>>>(erow, rptr);    // 391 blocks
    spmm_csr<<<(NNODES + 3) / 4, 256, 0, stream>>>(rptr, ecol, eval_, S, bias, out);
}

// Round 3
// 94.862 us; speedup vs baseline: 2.6495x; 1.4037x over previous
//
#include <hip/hip_runtime.h>

typedef unsigned int uint;
typedef unsigned short ushort;
typedef __attribute__((ext_vector_type(4))) float f32x4;
typedef __attribute__((ext_vector_type(4))) uint u32x4;
typedef __attribute__((ext_vector_type(2))) uint u32x2;

#define NNODES 100000
#define NEDGES 1600000
#define FD 128
#define BM 64

// round-to-nearest-even f32 -> bf16 (scalar)
__device__ __forceinline__ ushort f2bf(float f) {
    uint u = __float_as_uint(f);
    u += 0x7fffu + ((u >> 16) & 1u);
    return (ushort)(u >> 16);
}
// packed f32x2 -> bf16x2 (RNE), lo -> bits[15:0]
__device__ __forceinline__ uint cvt_pk_bf16(float lo, float hi) {
    uint r;
    asm("v_cvt_pk_bf16_f32 %0, %1, %2" : "=v"(r) : "v"(lo), "v"(hi));
    return r;
}
// swizzled byte offset in a [rows][128] bf16 tile (T2: kills 16-way conflicts)
__device__ __forceinline__ int swz(int row, int k) {
    return (row * 256 + k * 2) ^ ((row & 7) << 4);
}
__device__ __forceinline__ float bflo(uint s) { return __uint_as_float(s << 16); }
__device__ __forceinline__ float bfhi(uint s) { return __uint_as_float(s & 0xffff0000u); }

// ---------------------------------------------------------------------------
// Pre-kernel: Wt[n][k] = bf16(W[k][n]), stored PRE-SWIZZLED so the GEMM can
// stage it with a flat copy and read fragments with the same XOR.
// ---------------------------------------------------------------------------
__global__ __launch_bounds__(256) void build_wt(const float* __restrict__ W,
                                                ushort* __restrict__ Wt) {
    const int sid = blockIdx.x * 256 + threadIdx.x;   // 4096 slots
    const int n = sid & 127, k0 = (sid >> 7) * 4;
    const float w0 = W[(k0 + 0) * FD + n];
    const float w1 = W[(k0 + 1) * FD + n];
    const float w2 = W[(k0 + 2) * FD + n];
    const float w3 = W[(k0 + 3) * FD + n];
    u32x2 p;
    p.x = cvt_pk_bf16(w0, w1);
    p.y = cvt_pk_bf16(w2, w3);
    *(u32x2*)((char*)Wt + swz(n, k0)) = p;            // 8B store, granule-safe
}

// ---------------------------------------------------------------------------
// Kernel: row_ptr[r] = lower_bound(edge_row, r)
// ---------------------------------------------------------------------------
__global__ __launch_bounds__(256) void build_rowptr(const int* __restrict__ rows,
                                                    int* __restrict__ ptr) {
    const int r = blockIdx.x * 256 + threadIdx.x;
    if (r > NNODES) return;
    int lo = 0, hi = NEDGES;
    while (lo < hi) {
        const int mid = (lo + hi) >> 1;
        const bool lt = rows[mid] < r;
        lo = lt ? mid + 1 : lo;
        hi = lt ? hi : mid;
    }
    ptr[r] = lo;
}

// ---------------------------------------------------------------------------
// GEMM: S = bf16(X @ W). 64x128 tile/block, full K=128 staged once.
// 4 waves x (16 rows each); 16x16x32 bf16 MFMA via inline asm.
// LDS 48 KB (A 16 KB + B 32 KB), both XOR-swizzled.
// ---------------------------------------------------------------------------
__global__ __launch_bounds__(256) void gemm_mfma(const float* __restrict__ X,
                                                 const ushort* __restrict__ Wt,
                                                 ushort* __restrict__ S) {
    __shared__ ushort As[BM * FD];   // 16 KB, swizzled
    __shared__ ushort Bs[FD * FD];   // 32 KB, swizzled (flat copy of Wt)
    const int tid = threadIdx.x;
    const int row0 = blockIdx.x * BM;

    // stage A: 64x128 f32 -> bf16, convert + swizzle. 8 iters, coalesced 16B.
    #pragma unroll
    for (int it = 0; it < 8; ++it) {
        const int idx = tid + it * 256;            // [0,2048)
        const int r = idx >> 5, k0 = (idx & 31) * 4;
        const int grow = min(row0 + r, NNODES - 1);
        const float4 g = *(const float4*)&X[grow * FD + k0];
        u32x2 p;
        p.x = cvt_pk_bf16(g.x, g.y);
        p.y = cvt_pk_bf16(g.z, g.w);
        *(u32x2*)((char*)As + swz(r, k0)) = p;
    }
    // stage B: flat 32 KB copy (already swizzled in global)
    #pragma unroll
    for (int it = 0; it < 8; ++it) {
        const int b = (tid + it * 256) * 16;
        *(u32x4*)((char*)Bs + b) = *(const u32x4*)((const char*)Wt + b);
    }
    __syncthreads();

    const int lane = tid & 63, wv = tid >> 6;
    const int l15 = lane & 15, kg = lane >> 4;
    const int arow = wv * 16 + l15;

    f32x4 acc[8];
    #pragma unroll
    for (int i = 0; i < 8; ++i) acc[i] = (f32x4)0.f;

    #pragma unroll
    for (int ks = 0; ks < 4; ++ks) {
        const int k0 = ks * 32 + kg * 8;
        const u32x4 a = *(const u32x4*)((const char*)As + swz(arow, k0));
        #pragma unroll
        for (int nf = 0; nf < 8; ++nf) {
            const u32x4 b = *(const u32x4*)((const char*)Bs + swz(nf * 16 + l15, k0));
            asm volatile("v_mfma_f32_16x16x32_bf16 %0, %1, %2, %0"
                         : "+v"(acc[nf]) : "v"(a), "v"(b));
        }
    }
    asm volatile("s_nop 7\ns_nop 7\ns_nop 7");   // MFMA -> VALU read hazard guard

    #pragma unroll
    for (int nf = 0; nf < 8; ++nf) {
        const int col = nf * 16 + l15;
        #pragma unroll
        for (int r = 0; r < 4; ++r) {
            const int grow = row0 + wv * 16 + kg * 4 + r;   // C/D: row=(lane>>4)*4+reg
            S[grow * FD + col] = f2bf(acc[nf][r]);
        }
    }
}

// ---------------------------------------------------------------------------
// SpMM: one wave per row; lane owns 2 features. 8-wide manual unroll ->
// 8 outstanding gathers/lane; edge meta scalarized (s_load path).
// ---------------------------------------------------------------------------
__global__ __launch_bounds__(256) void spmm_csr(const int* __restrict__ ptr,
                                                const int* __restrict__ cols,
                                                const float* __restrict__ vals,
                                                const ushort* __restrict__ S,
                                                const float* __restrict__ bias,
                                                float* __restrict__ out) {
    const int row = (blockIdx.x * 256 + threadIdx.x) >> 6;   // exact grid
    const int lane = threadIdx.x & 63;
    const int f = lane * 2;
    const int e0 = __builtin_amdgcn_readfirstlane(ptr[row]);
    const int e1 = __builtin_amdgcn_readfirstlane(ptr[row + 1]);

    float ax[4] = {0.f, 0.f, 0.f, 0.f};
    float ay[4] = {0.f, 0.f, 0.f, 0.f};

    int e = e0;
    for (; e + 8 <= e1; e += 8) {
        int c[8]; float v[8]; uint s[8];
        #pragma unroll
        for (int j = 0; j < 8; ++j) { c[j] = cols[e + j]; v[j] = vals[e + j]; }
        #pragma unroll
        for (int j = 0; j < 8; ++j) s[j] = *(const uint*)&S[c[j] * FD + f];
        #pragma unroll
        for (int j = 0; j < 8; ++j) {
            ax[j & 3] = fmaf(v[j], bflo(s[j]), ax[j & 3]);
            ay[j & 3] = fmaf(v[j], bfhi(s[j]), ay[j & 3]);
        }
    }
    for (; e < e1; ++e) {
        const int c = cols[e];
        const float v = vals[e];
        const uint s = *(const uint*)&S[c * FD + f];
        ax[0] = fmaf(v, bflo(s), ax[0]);
        ay[0] = fmaf(v, bfhi(s), ay[0]);
    }

    float2 o;
    o.x = ((ax[0] + ax[1]) + (ax[2] + ax[3])) + bias[f];
    o.y = ((ay[0] + ay[1]) + (ay[2] + ay[3])) + bias[f + 1];
    *(float2*)&out[row * FD + f] = o;
}

// ---------------------------------------------------------------------------
extern "C" void kernel_launch(void* const* d_in, const int* in_sizes, int n_in,
                              void* d_out, int out_size, void* d_ws, size_t ws_size,
                              hipStream_t stream) {
    const float* X    = (const float*)d_in[0];
    const int*   erow = (const int*)d_in[1];
    const int*   ecol = (const int*)d_in[2];
    const float* eval_= (const float*)d_in[3];
    const float* W    = (const float*)d_in[4];
    const float* bias = (const float*)d_in[5];
    float* out = (float*)d_out;

    ushort* S   = (ushort*)d_ws;                               // 100032*128*2 = 25.6 MB
    ushort* Wt  = (ushort*)((char*)d_ws + 26u * 1024 * 1024);  // 32 KB
    int*    rpt = (int*)((char*)d_ws + 28u * 1024 * 1024);     // 100001 ints

    build_wt<<<16, 256, 0, stream>>>(W, Wt);
    build_rowptr<<<(NNODES + 256) / 256, 256, 0, stream>>>(erow, rpt);
    gemm_mfma<<<(NNODES + BM - 1) / BM, 256, 0, stream>>>(X, Wt, S);   // 1563 blocks
    spmm_csr<<<NNODES / 4, 256, 0, stream>>>(rpt, ecol, eval_, S, bias, out);
}